// Round 10
// baseline (933.373 us; speedup 1.0000x reference)
//
#include <hip/hip_runtime.h>
#include <hip/hip_bf16.h>
#include <stdint.h>

#define N_VOX 300000
#define KNB   27
#define COUT  96
#define EPS   1e-5f
#define BM    256
#define NBLK  ((N_VOX + BM - 1) / BM)   // 1172
#define QS_H  (255.0f / 6.0f)           // h quant: q = round(h*QS_H) - 128
#define XCLAMP 4.2f                     // x ~ N(0,1); clipped tail diffuses via conv2
#define QS_X  (127.0f / XCLAMP)

typedef __attribute__((ext_vector_type(8))) short  short8;
typedef __attribute__((ext_vector_type(4))) float  f32x4;
typedef __attribute__((ext_vector_type(4))) float  float4v;
typedef __attribute__((ext_vector_type(4))) unsigned short ushort4v;
typedef __attribute__((ext_vector_type(4))) int    int4v;
typedef __attribute__((ext_vector_type(2))) unsigned int uint2v;

__device__ __forceinline__ unsigned short f2bf(float f) {
    uint32_t u = __float_as_uint(f);
    uint32_t r = (u + 0x7FFFu + ((u >> 16) & 1u)) >> 16;
    return (unsigned short)r;
}
__device__ __forceinline__ float bf2f(unsigned short b) {
    return __uint_as_float(((uint32_t)b) << 16);
}

// barrier that does NOT drain vmcnt
__device__ __forceinline__ void barrier_lgkm() {
    asm volatile("s_waitcnt lgkmcnt(0)" ::: "memory");
    __builtin_amdgcn_s_barrier();
    asm volatile("" ::: "memory");
}

// ---------------- quantize x: f32 -> int8 (fixed clamp scale), 16 elems/thread ----------------
__global__ void cast_xq_kernel(const float4v* __restrict__ x, int4v* __restrict__ xq, int n16) {
    int i = blockIdx.x * blockDim.x + threadIdx.x;
    int stride = gridDim.x * blockDim.x;
    for (; i < n16; i += stride) {
        int4v o;
#pragma unroll
        for (int g = 0; g < 4; ++g) {
            float4v v = x[i * 4 + g];
            unsigned int packed = 0;
#pragma unroll
            for (int j = 0; j < 4; ++j) {
                int q = (int)floorf(v[j] * QS_X + 0.5f);
                q = q > 127 ? 127 : (q < -127 ? -127 : q);
                packed |= ((unsigned int)(q & 0xff)) << (8 * j);
            }
            o[g] = (int)packed;
        }
        xq[i] = o;
    }
}

// ---------------- |W| absmax reduction ----------------
__global__ void wmax_kernel(const float* __restrict__ W, int n, unsigned int* __restrict__ wmax_bits) {
    int tid = threadIdx.x;
    float m = 0.f;
    for (int i = blockIdx.x * blockDim.x + tid; i < n; i += gridDim.x * blockDim.x)
        m = fmaxf(m, fabsf(W[i]));
#pragma unroll
    for (int off = 1; off <= 32; off <<= 1) m = fmaxf(m, __shfl_xor(m, off));
    __shared__ float red[4];
    int wid = tid >> 6;
    if ((tid & 63) == 0) red[wid] = m;
    __syncthreads();
    if (tid == 0) {
        m = fmaxf(fmaxf(red[0], red[1]), fmaxf(red[2], red[3]));
        atomicMax(wmax_bits, __float_as_uint(m));
    }
}

__device__ __forceinline__ int quant_w(float v, float qs) {
    int iv = (int)floorf(v * qs + 0.5f);
    return iv > 127 ? 127 : (iv < -127 ? -127 : iv);
}

// ------------- W1 -> exact 15-bit hi/lo int8 planes, staging-unit layout -------------
__global__ void cast_w1q_kernel(const float* __restrict__ W1, signed char* __restrict__ W1q,
                                const unsigned int* __restrict__ wmax_bits, int total) {
    int idx = blockIdx.x * blockDim.x + threadIdx.x;
    if (idx >= total) return;
    float w1max = __uint_as_float(*wmax_bits);
    float qs = 16256.0f / w1max;
    int j    = idx & 15;
    int l    = (idx >> 4) & 63;
    int rest = idx >> 10;
    int p    = rest & 1;
    int cfk  = rest >> 1;
    int cf   = cfk % 6;
    int k    = cfk / 6;
    int ci   = ((l >> 4) << 4) + j;
    int co   = cf * 16 + (l & 15);
    float v = W1[(k * 64 + ci) * 96 + co] * qs;
    int wi = (int)floorf(v + 0.5f);
    wi = wi > 16256 ? 16256 : (wi < -16256 ? -16256 : wi);
    int hi = (wi + 64) >> 7;
    int lo = wi - (hi << 7);
    W1q[idx] = (signed char)(p == 0 ? hi : lo);
}

// ------------- W2 -> int8, K-padded-to-128 staging-unit layout -------------
__global__ void cast_w2q_kernel(const float* __restrict__ W2, signed char* __restrict__ W2q,
                                const unsigned int* __restrict__ wmax_bits, int total) {
    int idx = blockIdx.x * blockDim.x + threadIdx.x;
    if (idx >= total) return;
    float wmax = __uint_as_float(*wmax_bits);
    float qs = 127.0f / wmax;
    int j  = idx & 15;
    int l  = (idx >> 4) & 63;
    int u  = (idx >> 10) & 1;
    int r2 = idx >> 11;
    int cf = r2 % 6;
    int k  = r2 / 6;
    int ci = 64 * u + ((l >> 4) << 4) + j;
    int co = cf * 16 + (l & 15);
    signed char q = 0;
    if (ci < 96) q = (signed char)quant_w(W2[(k * 96 + ci) * 96 + co], qs);
    W2q[idx] = q;
}

// ------------- offset-correction: C[co] = 128 * sw * sum_{k,ci} qw[k][ci][co] -------------
__global__ void colsumq_kernel(const float* __restrict__ W2,
                               const unsigned int* __restrict__ wmax_bits,
                               float* __restrict__ Ccorr) {
    int co  = blockIdx.x;
    int tid = threadIdx.x;
    float wmax = __uint_as_float(*wmax_bits);
    float qs = 127.0f / wmax;
    int s = 0;
    for (int e = tid; e < KNB * 96; e += 256)
        s += quant_w(W2[e * 96 + co], qs);
#pragma unroll
    for (int off = 1; off <= 32; off <<= 1) s += __shfl_xor(s, off);
    __shared__ int red[4];
    int wid = tid >> 6;
    if ((tid & 63) == 0) red[wid] = s;
    __syncthreads();
    if (tid == 0) {
        s = red[0] + red[1] + red[2] + red[3];
        float sw = (6.0f / 255.0f) * wmax / 127.0f;
        Ccorr[co] = 128.0f * sw * (float)s;
    }
}

// ---------------- conv1 (int8 x, exact hi/lo W1), distance-2 A-prefetch, LDS-staged epilogue ----------------
__launch_bounds__(512, 4)
__global__ void conv1_i8_kernel(const signed char* __restrict__ Xq,
                                const int* __restrict__ nbrs,
                                const signed char* __restrict__ W1q,
                                const unsigned int* __restrict__ wmax_bits,
                                unsigned short* __restrict__ out,
                                float* __restrict__ partials) {
    // one shared pool, carved: nbr_s (27648) + bbuf (2x12288) = 52224 B.
    // After the K-loop it is reused: stat overlay (6144 B at +27648), then the
    // 256x100-short output staging tile (51200 B from offset 0).
    __shared__ __align__(16) char smem[52224];
    int* nbr_s = (int*)smem;
    signed char (*bbuf)[12288] = (signed char (*)[12288])(smem + 27648);

    const int tid  = threadIdx.x;
    const int blk  = blockIdx.x;
    const int base = blk * BM;
    const int w    = tid >> 6;
    const int l    = tid & 63;
    const int lo   = l & 15;
    const int hi   = l >> 4;

    const float w1max = __uint_as_float(*wmax_bits);
    const float s1 = (XCLAMP / 127.0f) * (w1max / 16256.0f);

    for (int i = tid; i < BM * KNB; i += 512) {
        int gi = base * KNB + i;
        nbr_s[i] = (gi < N_VOX * KNB) ? nbrs[gi] : 0;
    }

    int4v acch[2][6], accl[2][6];
#pragma unroll
    for (int f = 0; f < 2; ++f)
#pragma unroll
        for (int cf = 0; cf < 6; ++cf) {
            acch[f][cf] = (int4v){0, 0, 0, 0};
            accl[f][cf] = (int4v){0, 0, 0, 0};
        }

    int4v aA[2], aB[2], aC[2], aD[2], stg[2];

    auto stage_load = [&](int k) {
        const signed char* src = W1q + (size_t)k * 12288;
#pragma unroll
        for (int n = 0; n < 2; ++n) {
            int c = w + n * 8;
            if (c < 12)
                stg[n] = *(const int4v*)(src + c * 1024 + l * 16);
        }
    };
    auto stage_write = [&](signed char* buf) {
#pragma unroll
        for (int n = 0; n < 2; ++n) {
            int c = w + n * 8;
            if (c < 12)
                *(int4v*)&buf[c * 1024 + l * 16] = stg[n];
        }
    };
    auto loadA = [&](int k, int4v (&a)[2]) {
#pragma unroll
        for (int f = 0; f < 2; ++f) {
            int v   = w * 32 + f * 16 + lo;
            int row = nbr_s[v * KNB + k];
            a[f] = *(const int4v*)(Xq + (size_t)row * 64 + hi * 16);
        }
    };
    auto mfmaP = [&](const signed char* buf, int4v (&a)[2]) {
#pragma unroll
        for (int cf = 0; cf < 6; ++cf) {
            int4v bh = *(const int4v*)&buf[(cf * 2 + 0) * 1024 + l * 16];
            int4v bl = *(const int4v*)&buf[(cf * 2 + 1) * 1024 + l * 16];
#pragma unroll
            for (int f = 0; f < 2; ++f) {
                acch[f][cf] = __builtin_amdgcn_mfma_i32_16x16x64_i8(a[f], bh, acch[f][cf], 0, 0, 0);
                accl[f][cf] = __builtin_amdgcn_mfma_i32_16x16x64_i8(a[f], bl, accl[f][cf], 0, 0, 0);
            }
        }
    };

    // prologue: B(0)->bbuf0; A(0)->aA, A(1)->aB (after nbr_s visible)
    stage_load(0);
    __syncthreads();
    stage_write(bbuf[0]);
    loadA(0, aA);
    loadA(1, aB);
    __syncthreads();

    // main loop: 4 k-steps per iteration; A prefetched 2 steps ahead
#pragma unroll 1
    for (int kk = 0; kk < 24; kk += 4) {
        stage_load(kk + 1); loadA(kk + 2, aC); mfmaP(bbuf[0], aA); stage_write(bbuf[1]); barrier_lgkm();
        stage_load(kk + 2); loadA(kk + 3, aD); mfmaP(bbuf[1], aB); stage_write(bbuf[0]); barrier_lgkm();
        stage_load(kk + 3); loadA(kk + 4, aA); mfmaP(bbuf[0], aC); stage_write(bbuf[1]); barrier_lgkm();
        stage_load(kk + 4); loadA(kk + 5, aB); mfmaP(bbuf[1], aD); stage_write(bbuf[0]); barrier_lgkm();
    }
    // tail: k = 24 (bbuf0,aA), 25 (bbuf1,aB), 26 (bbuf0,aC)
    stage_load(25); loadA(26, aC); mfmaP(bbuf[0], aA); stage_write(bbuf[1]); barrier_lgkm();
    stage_load(26);                mfmaP(bbuf[1], aB); stage_write(bbuf[0]); barrier_lgkm();
    mfmaP(bbuf[0], aC);
    __syncthreads();

    // ---- stats (from registers, pre-rounding) ----
    float s_sum[6], s_sq[6];
#pragma unroll
    for (int cf = 0; cf < 6; ++cf) { s_sum[cf] = 0.f; s_sq[cf] = 0.f; }
#pragma unroll
    for (int f = 0; f < 2; ++f) {
        int m0 = base + w * 32 + f * 16 + hi * 4;
#pragma unroll
        for (int i = 0; i < 4; ++i) {
            if (m0 + i < N_VOX) {
#pragma unroll
                for (int cf = 0; cf < 6; ++cf) {
                    int comb = (acch[f][cf][i] << 7) + accl[f][cf][i];
                    float val = s1 * (float)comb;
                    s_sum[cf] += val;
                    s_sq[cf]  += val * val;
                }
            }
        }
    }
    float* stat = (float*)(smem + 27648);
#pragma unroll
    for (int cf = 0; cf < 6; ++cf) {
        float s = s_sum[cf], q = s_sq[cf];
        s += __shfl_xor(s, 16); q += __shfl_xor(q, 16);
        s += __shfl_xor(s, 32); q += __shfl_xor(q, 32);
        if (hi == 0) {
            stat[w * 192 + cf * 16 + lo]        = s;
            stat[w * 192 + COUT + cf * 16 + lo] = q;
        }
    }
    __syncthreads();
    if (tid < 2 * COUT) {
        float v = 0.f;
#pragma unroll
        for (int ww = 0; ww < 8; ++ww) v += stat[ww * 192 + tid];
        partials[blk * (2 * COUT) + tid] = v;
    }
    __syncthreads();

    // ---- stage output tile in LDS (row stride 100 shorts: hi-groups on distinct banks) ----
    unsigned short* ostage = (unsigned short*)smem;   // 256*100*2 = 51200 B
#pragma unroll
    for (int f = 0; f < 2; ++f) {
        int r0 = w * 32 + f * 16 + hi * 4;
#pragma unroll
        for (int i = 0; i < 4; ++i) {
#pragma unroll
            for (int cf = 0; cf < 6; ++cf) {
                int comb = (acch[f][cf][i] << 7) + accl[f][cf][i];
                ostage[(r0 + i) * 100 + cf * 16 + lo] = f2bf(s1 * (float)comb);
            }
        }
    }
    __syncthreads();

    // ---- coalesced copy-out: 16B/lane, 1KB/wave contiguous ----
    char* gout = (char*)out + (size_t)base * 192;
    for (int c = tid; c < 3072; c += 512) {
        int row = c / 12;
        int off = c - row * 12;
        if (base + row < N_VOX) {
            int4v v = *(const int4v*)((const char*)ostage + row * 200 + off * 16);
            *(int4v*)(gout + c * 16) = v;
        }
    }
}

// ---------------- conv2 (int8, offset-coded): unchanged from r7/r9 ----------------
template <bool OUT_BF16>
__launch_bounds__(512, 4)
__global__ void conv2_i8_kernel(const signed char* __restrict__ H8,
                                const int* __restrict__ nbrs,
                                const signed char* __restrict__ W2q,
                                const unsigned int* __restrict__ wmax_bits,
                                const float* __restrict__ Ccorr,
                                void* __restrict__ out,
                                float* __restrict__ partials) {
    __shared__ int nbr_s[BM * KNB];
    __shared__ __align__(16) signed char bbuf[2][12288];

    const int tid  = threadIdx.x;
    const int blk  = blockIdx.x;
    const int base = blk * BM;
    const int w    = tid >> 6;
    const int l    = tid & 63;
    const int lo   = l & 15;
    const int hi   = l >> 4;

    const float wmax = __uint_as_float(*wmax_bits);
    const float sw   = (6.0f / 255.0f) * wmax / 127.0f;

    for (int i = tid; i < BM * KNB; i += 512) {
        int gi = base * KNB + i;
        nbr_s[i] = (gi < N_VOX * KNB) ? nbrs[gi] : 0;
    }

    int4v acc[2][6];
#pragma unroll
    for (int f = 0; f < 2; ++f)
#pragma unroll
        for (int cf = 0; cf < 6; ++cf)
            acc[f][cf] = (int4v){0, 0, 0, 0};

    int4v a0[2][2], a1[2][2], stg[2];

    auto stage_load = [&](int k) {
        const signed char* src = W2q + (size_t)k * 12288;
#pragma unroll
        for (int n = 0; n < 2; ++n) {
            int c = w + n * 8;
            if (c < 12)
                stg[n] = *(const int4v*)(src + c * 1024 + l * 16);
        }
    };
    auto stage_write = [&](signed char* buf) {
#pragma unroll
        for (int n = 0; n < 2; ++n) {
            int c = w + n * 8;
            if (c < 12)
                *(int4v*)&buf[c * 1024 + l * 16] = stg[n];
        }
    };
    auto loadA = [&](int k, int4v (&a)[2][2]) {
#pragma unroll
        for (int f = 0; f < 2; ++f) {
            int v   = w * 32 + f * 16 + lo;
            int row = nbr_s[v * KNB + k];
            const signed char* hp = H8 + (size_t)row * 96;
            a[f][0] = *(const int4v*)(hp + hi * 16);
            a[f][1] = (hi < 2) ? *(const int4v*)(hp + 64 + hi * 16)
                               : (int4v){0, 0, 0, 0};
        }
    };
    auto mfmaP = [&](const signed char* buf, int4v (&a)[2][2]) {
#pragma unroll
        for (int cf = 0; cf < 6; ++cf)
#pragma unroll
            for (int u = 0; u < 2; ++u) {
                int4v b = *(const int4v*)&buf[(cf * 2 + u) * 1024 + l * 16];
                acc[0][cf] = __builtin_amdgcn_mfma_i32_16x16x64_i8(a[0][u], b, acc[0][cf], 0, 0, 0);
                acc[1][cf] = __builtin_amdgcn_mfma_i32_16x16x64_i8(a[1][u], b, acc[1][cf], 0, 0, 0);
            }
    };

    stage_load(0);
    __syncthreads();
    stage_write(bbuf[0]);
    loadA(0, a0);
    __syncthreads();

#pragma unroll 1
    for (int kk = 0; kk < KNB - 1; kk += 2) {
        stage_load(kk + 1);
        loadA(kk + 1, a1);
        mfmaP(bbuf[0], a0);
        stage_write(bbuf[1]);
        barrier_lgkm();
        stage_load(kk + 2);
        loadA(kk + 2, a0);
        mfmaP(bbuf[1], a1);
        stage_write(bbuf[0]);
        barrier_lgkm();
    }
    mfmaP(bbuf[0], a0);
    __syncthreads();

    float cc[6];
#pragma unroll
    for (int cf = 0; cf < 6; ++cf) cc[cf] = Ccorr[cf * 16 + lo];

    float s_sum[6], s_sq[6];
#pragma unroll
    for (int cf = 0; cf < 6; ++cf) { s_sum[cf] = 0.f; s_sq[cf] = 0.f; }

#pragma unroll
    for (int f = 0; f < 2; ++f) {
        int m0 = base + w * 32 + f * 16 + hi * 4;
#pragma unroll
        for (int i = 0; i < 4; ++i) {
            int m = m0 + i;
            bool valid = (m < N_VOX);
#pragma unroll
            for (int cf = 0; cf < 6; ++cf) {
                float val = sw * (float)acc[f][cf][i] + cc[cf];
                int col = cf * 16 + lo;
                if (valid) {
                    if (OUT_BF16) ((unsigned short*)out)[(size_t)m * COUT + col] = f2bf(val);
                    else          ((float*)out)[(size_t)m * COUT + col] = val;
                    s_sum[cf] += val;
                    s_sq[cf]  += val * val;
                }
            }
        }
    }

    float* stat = (float*)bbuf;
#pragma unroll
    for (int cf = 0; cf < 6; ++cf) {
        float s = s_sum[cf], q = s_sq[cf];
        s += __shfl_xor(s, 16); q += __shfl_xor(q, 16);
        s += __shfl_xor(s, 32); q += __shfl_xor(q, 32);
        if (hi == 0) {
            stat[w * 192 + cf * 16 + lo]        = s;
            stat[w * 192 + COUT + cf * 16 + lo] = q;
        }
    }
    __syncthreads();
    if (tid < 2 * COUT) {
        float v = 0.f;
#pragma unroll
        for (int ww = 0; ww < 8; ++ww) v += stat[ww * 192 + tid];
        partials[blk * (2 * COUT) + tid] = v;
    }
}

// ---------------- finalize: partials -> fused scale/bias ----------------
__global__ void finalize_kernel(const float* __restrict__ partials, int nblk,
                                const float* __restrict__ gamma, const float* __restrict__ beta,
                                float* __restrict__ scale, float* __restrict__ bias) {
    int c = blockIdx.x;
    int tid = threadIdx.x;
    float s = 0.f, q = 0.f;
    for (int b = tid; b < nblk; b += 256) {
        s += partials[b * 192 + c];
        q += partials[b * 192 + 96 + c];
    }
    __shared__ float rs[4], rq[4];
#pragma unroll
    for (int m = 1; m <= 32; m <<= 1) { s += __shfl_xor(s, m); q += __shfl_xor(q, m); }
    int wid = tid >> 6, lane = tid & 63;
    if (lane == 0) { rs[wid] = s; rq[wid] = q; }
    __syncthreads();
    if (tid == 0) {
        s = rs[0] + rs[1] + rs[2] + rs[3];
        q = rq[0] + rq[1] + rq[2] + rq[3];
        float mu  = s / (float)N_VOX;
        float var = q / (float)N_VOX - mu * mu;
        float rsg = rsqrtf(var + EPS);
        float sc  = gamma[c] * rsg;
        scale[c] = sc;
        bias[c]  = beta[c] - mu * sc;
    }
}

// ---------------- BN1+ReLU+quantize: h0 bf16 raw -> h8 int8 (offset-coded) ----------------
__global__ void bnrelu_quant_kernel(const unsigned short* __restrict__ h,
                                    const float* __restrict__ scale,
                                    const float* __restrict__ bias,
                                    signed char* __restrict__ h8, int n8) {
    __shared__ float sc[COUT], bi[COUT];
    if (threadIdx.x < COUT) { sc[threadIdx.x] = scale[threadIdx.x]; bi[threadIdx.x] = bias[threadIdx.x]; }
    __syncthreads();
    int i = blockIdx.x * blockDim.x + threadIdx.x;
    int stride = gridDim.x * blockDim.x;
    for (; i < n8; i += stride) {
        int e  = i * 8;
        int c0 = e % COUT;
        short8 v = *(const short8*)(h + e);
        unsigned int w0 = 0, w1 = 0;
#pragma unroll
        for (int j = 0; j < 4; ++j) {
            float f0 = fmaxf(bf2f((unsigned short)v[j])     * sc[c0 + j]     + bi[c0 + j], 0.f);
            float f1 = fmaxf(bf2f((unsigned short)v[j + 4]) * sc[c0 + j + 4] + bi[c0 + j + 4], 0.f);
            int q0 = (int)(f0 * QS_H + 0.5f) - 128; q0 = q0 > 127 ? 127 : q0;
            int q1 = (int)(f1 * QS_H + 0.5f) - 128; q1 = q1 > 127 ? 127 : q1;
            w0 |= ((unsigned int)(q0 & 0xff)) << (8 * j);
            w1 |= ((unsigned int)(q1 & 0xff)) << (8 * j);
        }
        uint2v o = {w0, w1};
        *(uint2v*)(h8 + e) = o;
    }
}

// ---------------- final BN+ReLU: bf16 raw -> f32 out, vectorized ----------------
__global__ void bnrelu_bf16_to_f32_kernel(const unsigned short* __restrict__ y,
                                          const float* __restrict__ scale,
                                          const float* __restrict__ bias,
                                          float* __restrict__ out, int n8) {
    __shared__ float sc[COUT], bi[COUT];
    if (threadIdx.x < COUT) { sc[threadIdx.x] = scale[threadIdx.x]; bi[threadIdx.x] = bias[threadIdx.x]; }
    __syncthreads();
    int i = blockIdx.x * blockDim.x + threadIdx.x;
    int stride = gridDim.x * blockDim.x;
    for (; i < n8; i += stride) {
        int e  = i * 8;
        int c0 = e % COUT;
        short8 v = *(const short8*)(y + e);
        float4v o0, o1;
#pragma unroll
        for (int j = 0; j < 4; ++j) {
            o0[j] = fmaxf(bf2f((unsigned short)v[j])     * sc[c0 + j]     + bi[c0 + j], 0.f);
            o1[j] = fmaxf(bf2f((unsigned short)v[j + 4]) * sc[c0 + j + 4] + bi[c0 + j + 4], 0.f);
        }
        *(float4v*)(out + e)     = o0;
        *(float4v*)(out + e + 4) = o1;
    }
}

// ---------------- BN-affine + ReLU, in-place f32 (fallback path) ----------------
__global__ void bnrelu_f32_kernel(float* __restrict__ h,
                                  const float* __restrict__ scale,
                                  const float* __restrict__ bias, int total) {
    __shared__ float sc[COUT], bi[COUT];
    if (threadIdx.x < COUT) { sc[threadIdx.x] = scale[threadIdx.x]; bi[threadIdx.x] = bias[threadIdx.x]; }
    __syncthreads();
    int i = blockIdx.x * blockDim.x + threadIdx.x;
    int stride = gridDim.x * blockDim.x;
    for (; i < total; i += stride) {
        int c = i % COUT;
        float v = h[i] * sc[c] + bi[c];
        h[i] = fmaxf(v, 0.f);
    }
}

extern "C" void kernel_launch(void* const* d_in, const int* in_sizes, int n_in,
                              void* d_out, int out_size, void* d_ws, size_t ws_size,
                              hipStream_t stream) {
    const float* x    = (const float*)d_in[0];
    const int*   nbrs = (const int*)  d_in[1];
    const float* W1   = (const float*)d_in[2];
    const float* g1   = (const float*)d_in[3];
    const float* b1   = (const float*)d_in[4];
    const float* W2   = (const float*)d_in[5];
    const float* g2   = (const float*)d_in[6];
    const float* b2   = (const float*)d_in[7];

    char* ws = (char*)d_ws;
    signed char*    xq  = (signed char*)(ws);                 // 19.2MB (dead after conv1)
    float*          p2  = (float*)(ws + 19200000);            // 1.8MB
    signed char*    h8  = (signed char*)(ws + 21000192);      // 28.8MB
    unsigned short* h0  = (unsigned short*)(ws + 50000128);   // 57.6MB (raw conv1 out)
    signed char*    w1q = (signed char*)(ws + 107600128);     // 331,776 B (hi/lo planes)
    signed char*    w2q = (signed char*)(ws + 107931904);     // 331,776 B
    float* p1    = (float*)(ws + 108263680);                  // 1.8MB
    float* sb    = (float*)(ws + 110063872);                  // 4KB
    float* scale1 = sb;
    float* bias1  = sb + 96;
    float* scale2 = sb + 192;
    float* bias2  = sb + 288;
    unsigned int* wmax2_bits = (unsigned int*)(sb + 384);     // byte 1536
    unsigned int* wmax1_bits = wmax2_bits + 1;                // byte 1540 (inside the 8-byte memset)
    float* Ccorr = sb + 448;                                  // 96 floats
    unsigned short* yraw = (unsigned short*)(ws + 110067968); // 57.6MB (if ws allows)

    const bool use_yraw = (ws_size >= (size_t)110067968 + 57600000);

    // 0) weight absmaxes + quantized weights (memset covers BOTH wmax words)
    hipMemsetAsync(wmax2_bits, 0, 8, stream);
    wmax_kernel<<<96, 256, 0, stream>>>(W2, KNB * 96 * 96, wmax2_bits);
    wmax_kernel<<<64, 256, 0, stream>>>(W1, KNB * 64 * 96, wmax1_bits);
    cast_w1q_kernel<<<(331776 + 255) / 256, 256, 0, stream>>>(W1, w1q, wmax1_bits, 331776);
    cast_w2q_kernel<<<(331776 + 255) / 256, 256, 0, stream>>>(W2, w2q, wmax2_bits, 331776);
    colsumq_kernel<<<96, 256, 0, stream>>>(W2, wmax2_bits, Ccorr);

    // 1) quantize x -> int8 (fixed clamp scale, single pass)
    cast_xq_kernel<<<2048, 256, 0, stream>>>((const float4v*)x, (int4v*)xq, N_VOX * 64 / 16);

    // 2) conv1 (int8, exact hi/lo W1) -> h0 raw bf16 (+ stats partials)
    conv1_i8_kernel<<<NBLK, 512, 0, stream>>>(xq, nbrs, w1q, wmax1_bits, h0, p1);

    // 3) BN1 finalize; BN1+ReLU+quantize -> h8 int8 (packed 96B rows, offset-coded)
    finalize_kernel<<<96, 256, 0, stream>>>(p1, NBLK, g1, b1, scale1, bias1);
    bnrelu_quant_kernel<<<4096, 256, 0, stream>>>(h0, scale1, bias1, h8, N_VOX * COUT / 8);

    if (use_yraw) {
        // 4) conv2 (int8) -> yraw bf16 (+ partials)
        conv2_i8_kernel<true><<<NBLK, 512, 0, stream>>>(h8, nbrs, w2q, wmax2_bits, Ccorr, yraw, p2);
        // 5) BN2 finalize + final affine/relu -> d_out f32
        finalize_kernel<<<96, 256, 0, stream>>>(p2, NBLK, g2, b2, scale2, bias2);
        bnrelu_bf16_to_f32_kernel<<<8192, 256, 0, stream>>>(yraw, scale2, bias2,
                                                            (float*)d_out, N_VOX * COUT / 8);
    } else {
        // fallback: conv2 writes f32 d_out, BN2 in place
        conv2_i8_kernel<false><<<NBLK, 512, 0, stream>>>(h8, nbrs, w2q, wmax2_bits, Ccorr, d_out, p2);
        finalize_kernel<<<96, 256, 0, stream>>>(p2, NBLK, g2, b2, scale2, bias2);
        bnrelu_f32_kernel<<<2048, 256, 0, stream>>>((float*)d_out, scale2, bias2, N_VOX * COUT);
    }
}

// Round 11
// 501.438 us; speedup vs baseline: 1.8614x; 1.8614x over previous
//
#include <hip/hip_runtime.h>
#include <hip/hip_bf16.h>
#include <stdint.h>

#define N_VOX 300000
#define KNB   27
#define COUT  96
#define EPS   1e-5f
#define BM    256
#define NBLK  ((N_VOX + BM - 1) / BM)   // 1172
#define QS_H  (255.0f / 6.0f)           // h quant: q = round(h*QS_H) - 128, 256 levels over [0,6]

typedef __attribute__((ext_vector_type(8))) short  short8;
typedef __attribute__((ext_vector_type(4))) float  f32x4;
typedef __attribute__((ext_vector_type(4))) float  float4v;
typedef __attribute__((ext_vector_type(4))) unsigned short ushort4v;
typedef __attribute__((ext_vector_type(4))) int    int4v;
typedef __attribute__((ext_vector_type(2))) unsigned int uint2v;

__device__ __forceinline__ unsigned short f2bf(float f) {
    uint32_t u = __float_as_uint(f);
    uint32_t r = (u + 0x7FFFu + ((u >> 16) & 1u)) >> 16;
    return (unsigned short)r;
}
__device__ __forceinline__ float bf2f(unsigned short b) {
    return __uint_as_float(((uint32_t)b) << 16);
}

// barrier that does NOT drain vmcnt: in-flight global gathers survive the
// rendezvous; only LDS ops must be complete/visible.
__device__ __forceinline__ void barrier_lgkm() {
    asm volatile("s_waitcnt lgkmcnt(0)" ::: "memory");
    __builtin_amdgcn_s_barrier();
    asm volatile("" ::: "memory");
}

// ---------------- cast x: f32 -> bf16, vectorized ----------------
__global__ void cast_x_kernel(const float4v* __restrict__ x, ushort4v* __restrict__ xb, int n4) {
    int i = blockIdx.x * blockDim.x + threadIdx.x;
    int stride = gridDim.x * blockDim.x;
    for (; i < n4; i += stride) {
        float4v v = x[i];
        ushort4v o;
        o.x = f2bf(v.x); o.y = f2bf(v.y); o.z = f2bf(v.z); o.w = f2bf(v.w);
        xb[i] = o;
    }
}

// ------------- cast + relayout W: [K][Cin][Cout] f32 -> staging-unit order bf16 -------------
template <int S>
__global__ void cast_w_kernel(const float* __restrict__ W, unsigned short* __restrict__ Wt,
                              int total) {
    int idx = blockIdx.x * blockDim.x + threadIdx.x;
    if (idx >= total) return;
    int j    = idx & 7;
    int ual  = idx >> 3;
    int lane = ual & 63;
    int lo   = lane & 15;
    int hi   = lane >> 4;
    int rest = ual >> 6;            // k*6*S + cf*S + s
    int s    = rest % S;
    int cfk  = rest / S;
    int cf   = cfk % 6;
    int k    = cfk / 6;
    int cin  = s * 32 + hi * 8 + j;
    int cout = cf * 16 + lo;
    Wt[idx] = f2bf(W[(k * (S * 32) + cin) * COUT + cout]);
}

// ---------------- |W2| absmax reduction (atomicMax on positive-float bits) ----------------
__global__ void wmax_kernel(const float* __restrict__ W, int n, unsigned int* __restrict__ wmax_bits) {
    int tid = threadIdx.x;
    float m = 0.f;
    for (int i = blockIdx.x * blockDim.x + tid; i < n; i += gridDim.x * blockDim.x)
        m = fmaxf(m, fabsf(W[i]));
#pragma unroll
    for (int off = 1; off <= 32; off <<= 1) m = fmaxf(m, __shfl_xor(m, off));
    __shared__ float red[4];
    int wid = tid >> 6;
    if ((tid & 63) == 0) red[wid] = m;
    __syncthreads();
    if (tid == 0) {
        m = fmaxf(fmaxf(red[0], red[1]), fmaxf(red[2], red[3]));
        atomicMax(wmax_bits, __float_as_uint(m));
    }
}

__device__ __forceinline__ int quant_w(float v, float qs) {
    int iv = (int)floorf(v * qs + 0.5f);
    return iv > 127 ? 127 : (iv < -127 ? -127 : iv);
}

// ------------- W2 -> int8, K-padded-to-128 staging-unit layout -------------
// byte idx = (((k*6 + cf)*2 + u)*64 + l)*16 + j holds
// W2[k][ci = 64u + 16*(l>>4) + j][cout = cf*16 + (l&15)] quantized, 0 if ci>=96.
__global__ void cast_w2q_kernel(const float* __restrict__ W2, signed char* __restrict__ W2q,
                                const unsigned int* __restrict__ wmax_bits, int total) {
    int idx = blockIdx.x * blockDim.x + threadIdx.x;
    if (idx >= total) return;
    float wmax = __uint_as_float(*wmax_bits);
    float qs = 127.0f / wmax;
    int j  = idx & 15;
    int l  = (idx >> 4) & 63;
    int u  = (idx >> 10) & 1;
    int r2 = idx >> 11;
    int cf = r2 % 6;
    int k  = r2 / 6;
    int ci = 64 * u + ((l >> 4) << 4) + j;
    int co = cf * 16 + (l & 15);
    signed char q = 0;
    if (ci < 96) q = (signed char)quant_w(W2[(k * 96 + ci) * 96 + co], qs);
    W2q[idx] = q;
}

// ------------- offset-correction: C[co] = 128 * sw * sum_{k,ci} qw[k][ci][co] -------------
// MUST replicate cast_w2q's quantization bit-exactly (same wmax, same rounding).
__global__ void colsumq_kernel(const float* __restrict__ W2,
                               const unsigned int* __restrict__ wmax_bits,
                               float* __restrict__ Ccorr) {
    int co  = blockIdx.x;     // 0..95
    int tid = threadIdx.x;    // 256
    float wmax = __uint_as_float(*wmax_bits);
    float qs = 127.0f / wmax;
    int s = 0;
    for (int e = tid; e < KNB * 96; e += 256)
        s += quant_w(W2[e * 96 + co], qs);
#pragma unroll
    for (int off = 1; off <= 32; off <<= 1) s += __shfl_xor(s, off);
    __shared__ int red[4];
    int wid = tid >> 6;
    if ((tid & 63) == 0) red[wid] = s;
    __syncthreads();
    if (tid == 0) {
        s = red[0] + red[1] + red[2] + red[3];
        float sw = (6.0f / 255.0f) * wmax / 127.0f;
        Ccorr[co] = 128.0f * sw * (float)s;
    }
}

// ---------------- conv1 (bf16): out[i] = sum_k X[nbr[i,k]] @ W[k] ----------------
template <int CIN, bool OUT_BF16>
__launch_bounds__(512, 4)
__global__ void conv_kernel(const unsigned short* __restrict__ X,
                            const int* __restrict__ nbrs,
                            const unsigned short* __restrict__ Wt,
                            void* __restrict__ out,
                            float* __restrict__ partials) {
    constexpr int S      = CIN / 32;
    constexpr int BUNITS = 6 * S * 64;
    constexpr int CHUNKS = BUNITS / 64;
    constexpr int NSTG   = (CHUNKS + 7) / 8;

    __shared__ int nbr_s[BM * KNB];
    __shared__ __align__(16) unsigned short bbuf[2][BUNITS * 8];

    const int tid  = threadIdx.x;
    const int blk  = blockIdx.x;
    const int base = blk * BM;
    const int w    = tid >> 6;
    const int l    = tid & 63;
    const int lo   = l & 15;
    const int hi   = l >> 4;

    for (int i = tid; i < BM * KNB; i += 512) {
        int gi = base * KNB + i;
        nbr_s[i] = (gi < N_VOX * KNB) ? nbrs[gi] : 0;
    }

    f32x4 acc[2][6];
#pragma unroll
    for (int f = 0; f < 2; ++f)
#pragma unroll
        for (int cf = 0; cf < 6; ++cf)
            acc[f][cf] = (f32x4){0.f, 0.f, 0.f, 0.f};

    short8 a0[2][S], a1[2][S], stg[NSTG];

    auto stage_load = [&](int k) {
        const unsigned short* src = Wt + (size_t)k * (BUNITS * 8);
#pragma unroll
        for (int n = 0; n < NSTG; ++n) {
            int c = w + n * 8;
            if (c < CHUNKS)
                stg[n] = *(const short8*)(src + c * 512 + l * 8);
        }
    };
    auto stage_write = [&](unsigned short* buf) {
#pragma unroll
        for (int n = 0; n < NSTG; ++n) {
            int c = w + n * 8;
            if (c < CHUNKS)
                *(short8*)&buf[c * 512 + l * 8] = stg[n];
        }
    };
    auto loadA = [&](int k, short8 (&a)[2][S]) {
#pragma unroll
        for (int f = 0; f < 2; ++f) {
            int v   = w * 32 + f * 16 + lo;
            int row = nbr_s[v * KNB + k];
            const unsigned short* xp = X + (size_t)row * CIN + hi * 8;
#pragma unroll
            for (int s = 0; s < S; ++s)
                a[f][s] = *(const short8*)(xp + s * 32);
        }
    };
    auto mfmaP = [&](const unsigned short* buf, short8 (&a)[2][S]) {
#pragma unroll
        for (int cf = 0; cf < 6; ++cf)
#pragma unroll
            for (int s = 0; s < S; ++s) {
                short8 b = *(const short8*)&buf[((cf * S + s) * 64 + l) * 8];
                acc[0][cf] = __builtin_amdgcn_mfma_f32_16x16x32_bf16(a[0][s], b, acc[0][cf], 0, 0, 0);
                acc[1][cf] = __builtin_amdgcn_mfma_f32_16x16x32_bf16(a[1][s], b, acc[1][cf], 0, 0, 0);
            }
    };

    stage_load(0);
    __syncthreads();
    stage_write(bbuf[0]);
    loadA(0, a0);
    __syncthreads();

#pragma unroll 1
    for (int kk = 0; kk < KNB - 1; kk += 2) {
        stage_load(kk + 1);
        loadA(kk + 1, a1);
        mfmaP(bbuf[0], a0);
        stage_write(bbuf[1]);
        barrier_lgkm();
        stage_load(kk + 2);
        loadA(kk + 2, a0);
        mfmaP(bbuf[1], a1);
        stage_write(bbuf[0]);
        barrier_lgkm();
    }
    mfmaP(bbuf[0], a0);
    __syncthreads();

    float s_sum[6], s_sq[6];
#pragma unroll
    for (int cf = 0; cf < 6; ++cf) { s_sum[cf] = 0.f; s_sq[cf] = 0.f; }

#pragma unroll
    for (int f = 0; f < 2; ++f) {
        int m0 = base + w * 32 + f * 16 + hi * 4;
#pragma unroll
        for (int i = 0; i < 4; ++i) {
            int m = m0 + i;
            bool valid = (m < N_VOX);
#pragma unroll
            for (int cf = 0; cf < 6; ++cf) {
                float val = acc[f][cf][i];
                int col = cf * 16 + lo;
                if (valid) {
                    if (OUT_BF16) ((unsigned short*)out)[(size_t)m * COUT + col] = f2bf(val);
                    else          ((float*)out)[(size_t)m * COUT + col] = val;
                    s_sum[cf] += val;
                    s_sq[cf]  += val * val;
                }
            }
        }
    }

    float* stat = (float*)bbuf;
#pragma unroll
    for (int cf = 0; cf < 6; ++cf) {
        float s = s_sum[cf], q = s_sq[cf];
        s += __shfl_xor(s, 16); q += __shfl_xor(q, 16);
        s += __shfl_xor(s, 32); q += __shfl_xor(q, 32);
        if (hi == 0) {
            stat[w * 192 + cf * 16 + lo]        = s;
            stat[w * 192 + COUT + cf * 16 + lo] = q;
        }
    }
    __syncthreads();
    if (tid < 2 * COUT) {
        float v = 0.f;
#pragma unroll
        for (int ww = 0; ww < 8; ++ww) v += stat[ww * 192 + tid];
        partials[blk * (2 * COUT) + tid] = v;
    }
}

// ---------------- conv2 (int8): out[i] = sw * sum_k Q[nbr[i,k]] @ W2q[k] + C[co] ----------------
// Q = h-quant MINUS 128 offset (uses full i8 range for h>=0); offset folded into
// C[co] = 128*sw*colsum(qw) (exact, quantized colsum). Rows packed 96B.
template <bool OUT_BF16>
__launch_bounds__(512, 4)
__global__ void conv2_i8_kernel(const signed char* __restrict__ H8,
                                const int* __restrict__ nbrs,
                                const signed char* __restrict__ W2q,
                                const unsigned int* __restrict__ wmax_bits,
                                const float* __restrict__ Ccorr,
                                void* __restrict__ out,
                                float* __restrict__ partials) {
    __shared__ int nbr_s[BM * KNB];                     // 27648 B
    __shared__ __align__(16) signed char bbuf[2][12288]; // 24576 B

    const int tid  = threadIdx.x;
    const int blk  = blockIdx.x;
    const int base = blk * BM;
    const int w    = tid >> 6;
    const int l    = tid & 63;
    const int lo   = l & 15;
    const int hi   = l >> 4;

    const float wmax = __uint_as_float(*wmax_bits);
    const float sw   = (6.0f / 255.0f) * wmax / 127.0f;

    for (int i = tid; i < BM * KNB; i += 512) {
        int gi = base * KNB + i;
        nbr_s[i] = (gi < N_VOX * KNB) ? nbrs[gi] : 0;
    }

    int4v acc[2][6];
#pragma unroll
    for (int f = 0; f < 2; ++f)
#pragma unroll
        for (int cf = 0; cf < 6; ++cf)
            acc[f][cf] = (int4v){0, 0, 0, 0};

    int4v a0[2][2], a1[2][2], stg[2];

    auto stage_load = [&](int k) {
        const signed char* src = W2q + (size_t)k * 12288;
#pragma unroll
        for (int n = 0; n < 2; ++n) {
            int c = w + n * 8;
            if (c < 12)
                stg[n] = *(const int4v*)(src + c * 1024 + l * 16);
        }
    };
    auto stage_write = [&](signed char* buf) {
#pragma unroll
        for (int n = 0; n < 2; ++n) {
            int c = w + n * 8;
            if (c < 12)
                *(int4v*)&buf[c * 1024 + l * 16] = stg[n];
        }
    };
    auto loadA = [&](int k, int4v (&a)[2][2]) {
#pragma unroll
        for (int f = 0; f < 2; ++f) {
            int v   = w * 32 + f * 16 + lo;
            int row = nbr_s[v * KNB + k];
            const signed char* hp = H8 + (size_t)row * 96;
            a[f][0] = *(const int4v*)(hp + hi * 16);
            a[f][1] = (hi < 2) ? *(const int4v*)(hp + 64 + hi * 16)
                               : (int4v){0, 0, 0, 0};
        }
    };
    auto mfmaP = [&](const signed char* buf, int4v (&a)[2][2]) {
#pragma unroll
        for (int cf = 0; cf < 6; ++cf)
#pragma unroll
            for (int u = 0; u < 2; ++u) {
                int4v b = *(const int4v*)&buf[(cf * 2 + u) * 1024 + l * 16];
                acc[0][cf] = __builtin_amdgcn_mfma_i32_16x16x64_i8(a[0][u], b, acc[0][cf], 0, 0, 0);
                acc[1][cf] = __builtin_amdgcn_mfma_i32_16x16x64_i8(a[1][u], b, acc[1][cf], 0, 0, 0);
            }
    };

    stage_load(0);
    __syncthreads();
    stage_write(bbuf[0]);
    loadA(0, a0);
    __syncthreads();

#pragma unroll 1
    for (int kk = 0; kk < KNB - 1; kk += 2) {
        stage_load(kk + 1);
        loadA(kk + 1, a1);
        mfmaP(bbuf[0], a0);
        stage_write(bbuf[1]);
        barrier_lgkm();
        stage_load(kk + 2);
        loadA(kk + 2, a0);
        mfmaP(bbuf[1], a1);
        stage_write(bbuf[0]);
        barrier_lgkm();
    }
    mfmaP(bbuf[0], a0);
    __syncthreads();

    // per-lane offset-correction constants (6 distinct cols per lane)
    float cc[6];
#pragma unroll
    for (int cf = 0; cf < 6; ++cf) cc[cf] = Ccorr[cf * 16 + lo];

    float s_sum[6], s_sq[6];
#pragma unroll
    for (int cf = 0; cf < 6; ++cf) { s_sum[cf] = 0.f; s_sq[cf] = 0.f; }

#pragma unroll
    for (int f = 0; f < 2; ++f) {
        int m0 = base + w * 32 + f * 16 + hi * 4;
#pragma unroll
        for (int i = 0; i < 4; ++i) {
            int m = m0 + i;
            bool valid = (m < N_VOX);
#pragma unroll
            for (int cf = 0; cf < 6; ++cf) {
                float val = sw * (float)acc[f][cf][i] + cc[cf];
                int col = cf * 16 + lo;
                if (valid) {
                    if (OUT_BF16) ((unsigned short*)out)[(size_t)m * COUT + col] = f2bf(val);
                    else          ((float*)out)[(size_t)m * COUT + col] = val;
                    s_sum[cf] += val;
                    s_sq[cf]  += val * val;
                }
            }
        }
    }

    float* stat = (float*)bbuf;
#pragma unroll
    for (int cf = 0; cf < 6; ++cf) {
        float s = s_sum[cf], q = s_sq[cf];
        s += __shfl_xor(s, 16); q += __shfl_xor(q, 16);
        s += __shfl_xor(s, 32); q += __shfl_xor(q, 32);
        if (hi == 0) {
            stat[w * 192 + cf * 16 + lo]        = s;
            stat[w * 192 + COUT + cf * 16 + lo] = q;
        }
    }
    __syncthreads();
    if (tid < 2 * COUT) {
        float v = 0.f;
#pragma unroll
        for (int ww = 0; ww < 8; ++ww) v += stat[ww * 192 + tid];
        partials[blk * (2 * COUT) + tid] = v;
    }
}

// ---------------- finalize: partials -> fused scale/bias ----------------
__global__ void finalize_kernel(const float* __restrict__ partials, int nblk,
                                const float* __restrict__ gamma, const float* __restrict__ beta,
                                float* __restrict__ scale, float* __restrict__ bias) {
    int c = blockIdx.x;
    int tid = threadIdx.x;
    float s = 0.f, q = 0.f;
    for (int b = tid; b < nblk; b += 256) {
        s += partials[b * 192 + c];
        q += partials[b * 192 + 96 + c];
    }
    __shared__ float rs[4], rq[4];
#pragma unroll
    for (int m = 1; m <= 32; m <<= 1) { s += __shfl_xor(s, m); q += __shfl_xor(q, m); }
    int wid = tid >> 6, lane = tid & 63;
    if (lane == 0) { rs[wid] = s; rq[wid] = q; }
    __syncthreads();
    if (tid == 0) {
        s = rs[0] + rs[1] + rs[2] + rs[3];
        q = rq[0] + rq[1] + rq[2] + rq[3];
        float mu  = s / (float)N_VOX;
        float var = q / (float)N_VOX - mu * mu;
        float rsg = rsqrtf(var + EPS);
        float sc  = gamma[c] * rsg;
        scale[c] = sc;
        bias[c]  = beta[c] - mu * sc;
    }
}

// ---------------- BN1+ReLU+quantize: h0 bf16 raw -> h8 int8 (offset-coded) ----------------
__global__ void bnrelu_quant_kernel(const unsigned short* __restrict__ h,
                                    const float* __restrict__ scale,
                                    const float* __restrict__ bias,
                                    signed char* __restrict__ h8, int n8) {
    __shared__ float sc[COUT], bi[COUT];
    if (threadIdx.x < COUT) { sc[threadIdx.x] = scale[threadIdx.x]; bi[threadIdx.x] = bias[threadIdx.x]; }
    __syncthreads();
    int i = blockIdx.x * blockDim.x + threadIdx.x;
    int stride = gridDim.x * blockDim.x;
    for (; i < n8; i += stride) {
        int e  = i * 8;
        int c0 = e % COUT;
        short8 v = *(const short8*)(h + e);
        unsigned int w0 = 0, w1 = 0;
#pragma unroll
        for (int j = 0; j < 4; ++j) {
            float f0 = fmaxf(bf2f((unsigned short)v[j])     * sc[c0 + j]     + bi[c0 + j], 0.f);
            float f1 = fmaxf(bf2f((unsigned short)v[j + 4]) * sc[c0 + j + 4] + bi[c0 + j + 4], 0.f);
            int q0 = (int)(f0 * QS_H + 0.5f) - 128; q0 = q0 > 127 ? 127 : q0;
            int q1 = (int)(f1 * QS_H + 0.5f) - 128; q1 = q1 > 127 ? 127 : q1;
            w0 |= ((unsigned int)(q0 & 0xff)) << (8 * j);
            w1 |= ((unsigned int)(q1 & 0xff)) << (8 * j);
        }
        uint2v o = {w0, w1};
        *(uint2v*)(h8 + e) = o;
    }
}

// ---------------- final BN+ReLU: bf16 raw -> f32 out, vectorized ----------------
__global__ void bnrelu_bf16_to_f32_kernel(const unsigned short* __restrict__ y,
                                          const float* __restrict__ scale,
                                          const float* __restrict__ bias,
                                          float* __restrict__ out, int n8) {
    __shared__ float sc[COUT], bi[COUT];
    if (threadIdx.x < COUT) { sc[threadIdx.x] = scale[threadIdx.x]; bi[threadIdx.x] = bias[threadIdx.x]; }
    __syncthreads();
    int i = blockIdx.x * blockDim.x + threadIdx.x;
    int stride = gridDim.x * blockDim.x;
    for (; i < n8; i += stride) {
        int e  = i * 8;
        int c0 = e % COUT;
        short8 v = *(const short8*)(y + e);
        float4v o0, o1;
#pragma unroll
        for (int j = 0; j < 4; ++j) {
            o0[j] = fmaxf(bf2f((unsigned short)v[j])     * sc[c0 + j]     + bi[c0 + j], 0.f);
            o1[j] = fmaxf(bf2f((unsigned short)v[j + 4]) * sc[c0 + j + 4] + bi[c0 + j + 4], 0.f);
        }
        *(float4v*)(out + e)     = o0;
        *(float4v*)(out + e + 4) = o1;
    }
}

// ---------------- BN-affine + ReLU, in-place f32 (fallback path) ----------------
__global__ void bnrelu_f32_kernel(float* __restrict__ h,
                                  const float* __restrict__ scale,
                                  const float* __restrict__ bias, int total) {
    __shared__ float sc[COUT], bi[COUT];
    if (threadIdx.x < COUT) { sc[threadIdx.x] = scale[threadIdx.x]; bi[threadIdx.x] = bias[threadIdx.x]; }
    __syncthreads();
    int i = blockIdx.x * blockDim.x + threadIdx.x;
    int stride = gridDim.x * blockDim.x;
    for (; i < total; i += stride) {
        int c = i % COUT;
        float v = h[i] * sc[c] + bi[c];
        h[i] = fmaxf(v, 0.f);
    }
}

extern "C" void kernel_launch(void* const* d_in, const int* in_sizes, int n_in,
                              void* d_out, int out_size, void* d_ws, size_t ws_size,
                              hipStream_t stream) {
    const float* x    = (const float*)d_in[0];
    const int*   nbrs = (const int*)  d_in[1];
    const float* W1   = (const float*)d_in[2];
    const float* g1   = (const float*)d_in[3];
    const float* b1   = (const float*)d_in[4];
    const float* W2   = (const float*)d_in[5];
    const float* g2   = (const float*)d_in[6];
    const float* b2   = (const float*)d_in[7];

    char* ws = (char*)d_ws;
    unsigned short* xb  = (unsigned short*)(ws);              // 38.4MB (dead after conv1)
    float*          p2  = (float*)(ws);                       // 1.8MB, overlays dead xb
    signed char*    h8  = (signed char*)(ws + 2097152);       // 28.8MB, overlays dead xb
    unsigned short* h0  = (unsigned short*)(ws + 38400000);   // 57.6MB (raw conv1 out)
    unsigned short* w1t = (unsigned short*)(ws + 96000000);   // 331,776 B
    signed char*    w2q = (signed char*)(ws + 96331776);      // 331,776 B (int8 W2)
    float* p1    = (float*)(ws + 96829440);                   // 1.8MB
    float* sb    = (float*)(ws + 98629632);                   // 3072 B
    float* scale1 = sb;
    float* bias1  = sb + 96;
    float* scale2 = sb + 192;
    float* bias2  = sb + 288;
    unsigned int* wmax_bits = (unsigned int*)(sb + 384);
    float* Ccorr = sb + 448;                                  // 96 floats
    unsigned short* yraw = (unsigned short*)(ws + 98632704);  // 57.6MB (if ws allows)

    const bool use_yraw = (ws_size >= (size_t)98632704 + 57600000);

    // 0) W2 absmax -> int8 W2 (staging-unit layout) + offset-correction colsums
    hipMemsetAsync(wmax_bits, 0, 4, stream);
    wmax_kernel<<<96, 256, 0, stream>>>(W2, KNB * 96 * 96, wmax_bits);
    cast_w2q_kernel<<<(331776 + 255) / 256, 256, 0, stream>>>(W2, w2q, wmax_bits, 331776);
    colsumq_kernel<<<96, 256, 0, stream>>>(W2, wmax_bits, Ccorr);

    // 1) casts for conv1
    cast_x_kernel<<<2048, 256, 0, stream>>>((const float4v*)x, (ushort4v*)xb, N_VOX * 64 / 4);
    {
        int tot1 = KNB * 64 * COUT;
        cast_w_kernel<2><<<(tot1 + 255) / 256, 256, 0, stream>>>(W1, w1t, tot1);
    }

    // 2) conv1 (Cin=64, bf16) -> h0 raw bf16 (+ stats partials)
    conv_kernel<64, true><<<NBLK, 512, 0, stream>>>(xb, nbrs, w1t, h0, p1);

    // 3) BN1 finalize; BN1+ReLU+quantize -> h8 int8 (packed 96B rows, offset-coded)
    finalize_kernel<<<96, 256, 0, stream>>>(p1, NBLK, g1, b1, scale1, bias1);
    bnrelu_quant_kernel<<<4096, 256, 0, stream>>>(h0, scale1, bias1, h8, N_VOX * COUT / 8);

    if (use_yraw) {
        // 4) conv2 (int8) -> yraw bf16 (+ partials)
        conv2_i8_kernel<true><<<NBLK, 512, 0, stream>>>(h8, nbrs, w2q, wmax_bits, Ccorr, yraw, p2);
        // 5) BN2 finalize + final affine/relu -> d_out f32
        finalize_kernel<<<96, 256, 0, stream>>>(p2, NBLK, g2, b2, scale2, bias2);
        bnrelu_bf16_to_f32_kernel<<<8192, 256, 0, stream>>>(yraw, scale2, bias2,
                                                            (float*)d_out, N_VOX * COUT / 8);
    } else {
        // fallback: conv2 writes f32 d_out, BN2 in place
        conv2_i8_kernel<false><<<NBLK, 512, 0, stream>>>(h8, nbrs, w2q, wmax_bits, Ccorr, d_out, p2);
        finalize_kernel<<<96, 256, 0, stream>>>(p2, NBLK, g2, b2, scale2, bias2);
        bnrelu_f32_kernel<<<2048, 256, 0, stream>>>((float*)d_out, scale2, bias2, N_VOX * COUT);
    }
}